// Round 3
// baseline (305.287 us; speedup 1.0000x reference)
//
#include <hip/hip_runtime.h>
#include <hip/hip_bf16.h>
#include <stdint.h>

// RSNN: T=256 steps, B=32, N_IN=256, N=2048.
// out = [3, T, B, N] fp32: zs | vs | z2s  (TBN elements each)
//
// Pipeline (all on `stream`, stream-ordered):
//   0. xt_k:       X fp32 [M][K] -> Xt [K][M]  (borrows zs out-region, pre-scan)
//   1. wt_convert: W_bern fp32 [k][n] -> Wt bf16 [n][k]   (ws +0, 8 MB)
//   2. in_gemm:    I = x @ W_in + b  (fp32, M=8192,K=256,N=2048) -> Ibuf
//                  128x128 tile, 8x8 micro, dbuf LDS + counted vmcnt pipeline
//   3. scan:       per-neuron serial v scan; writes zs, vs (fp32) and Z bf16 (ws +8MB)
//   4. bern_gemm:  Y = Z @ W_bern  (bf16 MFMA, M=8192,N=2048,K=2048) -> z2 region
//   5. gather_k:   z2[t,b,j] = Y[t,b,idx[t,j]]  in place (row via LDS)

#define T_STEPS 256
#define BATCH   32
#define NIN     256
#define NN      2048
#define BN_FLAT (BATCH * NN)            // 65536
#define TBN     (T_STEPS * BATCH * NN)  // 16777216
#define MROWS   (T_STEPS * BATCH)       // 8192

typedef __attribute__((ext_vector_type(4))) float fx4;
typedef __attribute__((ext_vector_type(4))) int   ix4;

__device__ __forceinline__ void gll16(const void* g, void* l) {
  typedef __attribute__((address_space(1))) void gvoid_t;
  typedef __attribute__((address_space(3))) void lvoid_t;
  __builtin_amdgcn_global_load_lds((gvoid_t*)(g), (lvoid_t*)(l), 16, 0, 0);
}

__device__ __forceinline__ void mfma16(fx4& d, ix4 a, ix4 b) {
  asm volatile("v_mfma_f32_16x16x32_bf16 %0, %1, %2, %0" : "+v"(d) : "v"(a), "v"(b));
}

// ---------------------------------------------------------------- kernel 0
// X [8192][256] -> Xt [256][8192]
__global__ __launch_bounds__(256) void xt_k(const float* __restrict__ X,
                                            float* __restrict__ Xt) {
  __shared__ float tile[32][33];
  const int m0 = blockIdx.x << 5, k0 = blockIdx.y << 5;
  const int tx = threadIdx.x, ty = threadIdx.y;
#pragma unroll
  for (int i = 0; i < 32; i += 8)
    tile[ty + i][tx] = X[(size_t)(m0 + ty + i) * NIN + k0 + tx];
  __syncthreads();
#pragma unroll
  for (int i = 0; i < 32; i += 8)
    Xt[(size_t)(k0 + ty + i) * MROWS + m0 + tx] = tile[tx][ty + i];
}

// ---------------------------------------------------------------- kernel 1
__global__ __launch_bounds__(256) void wt_convert(const float* __restrict__ W,
                                                  __hip_bfloat16* __restrict__ Wt) {
  __shared__ float tile[32][33];
  const int k0 = blockIdx.y << 5, n0 = blockIdx.x << 5;
  const int tx = threadIdx.x, ty = threadIdx.y;
#pragma unroll
  for (int i = 0; i < 32; i += 8)
    tile[ty + i][tx] = W[(size_t)(k0 + ty + i) * NN + n0 + tx];
  __syncthreads();
#pragma unroll
  for (int i = 0; i < 32; i += 8)
    Wt[(size_t)(n0 + ty + i) * NN + k0 + tx] = __float2bfloat16(tile[tx][ty + i]);
}

// ---------------------------------------------------------------- kernel 2
// fp32 GEMM: I[8192][2048] = Xt^T @ Wi + bias.
// 128x128 block tile, 256 threads, 8x8 micro (cols split 4+4 at +64), BK=16.
// Double-buffered LDS, counted vmcnt(4) so the next tile's global_load_lds
// stay in flight across the barrier (never drain to 0 in-loop).
// LDS reads conflict-free: A 4-addr/wave 16-way bcast, B 16-addr 2-way.
__global__ __launch_bounds__(256) void in_gemm(const float* __restrict__ Xt,
                                               const float* __restrict__ Wi,
                                               const float* __restrict__ bias,
                                               float* __restrict__ I) {
  __shared__ __align__(16) float As[2][16 * 128];  // [k][m] 8 KB each
  __shared__ __align__(16) float Bs[2][16 * 128];  // [k][n] 8 KB each
  const int tid = threadIdx.x;
  const int tm = tid >> 4;   // 0..15 -> rows tm*8..+7
  const int tn = tid & 15;   // 0..15 -> cols {tn*4..+3} u {64+tn*4..+3}
  const int m0 = blockIdx.x * 128, n0 = blockIdx.y * 128;

  fx4 acc[8][2] = {};

  // staging: unit u = tid + i*256 (i=0,1): row = u>>5, col4 = (u&31)*4
  // LDS dest linear at u*16 bytes (wave-uniform base + lane*16).
  const int srow = tid >> 5;            // 0..7 (i=0), +8 (i=1)
  const int scol = (tid & 31) * 4;
  const float* gA = Xt + (size_t)srow * MROWS + m0 + scol;
  const float* gB = Wi + (size_t)srow * NN + n0 + scol;

#define STAGE_IG(bi)                                                  \
  do {                                                                \
    gll16(gA, (char*)As[bi] + tid * 16);                              \
    gll16(gA + 8 * MROWS, (char*)As[bi] + tid * 16 + 4096);           \
    gll16(gB, (char*)Bs[bi] + tid * 16);                              \
    gll16(gB + 8 * NN, (char*)Bs[bi] + tid * 16 + 4096);              \
    gA += (size_t)16 * MROWS;                                         \
    gB += (size_t)16 * NN;                                            \
  } while (0)

#define COMPUTE_IG(bi)                                                \
  do {                                                                \
    _Pragma("unroll") for (int kk = 0; kk < 16; ++kk) {               \
      const float* ar = &As[bi][kk * 128 + tm * 8];                   \
      const float* br = &Bs[bi][kk * 128 + tn * 4];                   \
      fx4 a0 = *(const fx4*)ar, a1 = *(const fx4*)(ar + 4);           \
      fx4 b0 = *(const fx4*)br, b1 = *(const fx4*)(br + 64);          \
      _Pragma("unroll") for (int r = 0; r < 4; ++r) {                 \
        _Pragma("unroll") for (int c = 0; c < 4; ++c) {               \
          acc[r][0][c] = fmaf(a0[r], b0[c], acc[r][0][c]);            \
          acc[r][1][c] = fmaf(a0[r], b1[c], acc[r][1][c]);            \
          acc[r + 4][0][c] = fmaf(a1[r], b0[c], acc[r + 4][0][c]);    \
          acc[r + 4][1][c] = fmaf(a1[r], b1[c], acc[r + 4][1][c]);    \
        }                                                             \
      }                                                               \
    }                                                                 \
  } while (0)

  STAGE_IG(0);
  for (int t = 0; t < 15; ++t) {
    STAGE_IG((t + 1) & 1);                       // prefetch next tile
    asm volatile("s_waitcnt vmcnt(4)" ::: "memory");  // current tile ready
    __builtin_amdgcn_s_barrier();
    COMPUTE_IG(t & 1);
    __builtin_amdgcn_s_barrier();                // before next overwrites buf
  }
  asm volatile("s_waitcnt vmcnt(0)" ::: "memory");
  __builtin_amdgcn_s_barrier();
  COMPUTE_IG(1);

#undef STAGE_IG
#undef COMPUTE_IG

#pragma unroll
  for (int r = 0; r < 8; ++r) {
    const size_t row = (size_t)(m0 + tm * 8 + r) * NN;
    fx4 r0, r1;
#pragma unroll
    for (int c = 0; c < 4; ++c) {
      r0[c] = acc[r][0][c] + bias[n0 + tn * 4 + c];
      r1[c] = acc[r][1][c] + bias[n0 + 64 + tn * 4 + c];
    }
    *(fx4*)&I[row + n0 + tn * 4] = r0;
    *(fx4*)&I[row + n0 + 64 + tn * 4] = r1;
  }
}

// ---------------------------------------------------------------- kernel 3
// Per-neuron serial scan over t. One thread per (b,n). Prefetch-unrolled x8.
// Matches numpy elementwise semantics: decay*v computed with separate
// mul+add (no fma contraction) so rounding matches the reference closely.
__device__ __forceinline__ void scan_body(float* zs, float* vsout,
                                          const float* I, __hip_bfloat16* Zb) {
  const int nid = blockIdx.x * 256 + threadIdx.x;  // 0..65535
  float v = 0.f;
  for (int t0 = 0; t0 < T_STEPS; t0 += 8) {
    float iin[8];
#pragma unroll
    for (int u = 0; u < 8; ++u)
      iin[u] = I[(size_t)(t0 + u) * BN_FLAT + nid];
#pragma unroll
    for (int u = 0; u < 8; ++u) {
      float nv = __fadd_rn(__fmul_rn(0.9048374180359595f, v), iin[u]);
      nv = fminf(fmaxf(nv, -1.0f), 1.01f);
      const bool sp = nv > 1.0f;        // == (new_v - THR) > 0 in fp32
      const float z = sp ? 1.0f : 0.0f;
      nv = sp ? -1.0f : nv;             // hard reset
      const size_t off = (size_t)(t0 + u) * BN_FLAT + nid;
      zs[off] = z;
      vsout[off] = nv;
      Zb[off] = __float2bfloat16(z);    // exact 0/1
      v = nv;
    }
  }
}

__global__ __launch_bounds__(256) void scan_sep(float* __restrict__ out,
                                                const float* __restrict__ I,
                                                __hip_bfloat16* __restrict__ Zb) {
  scan_body(out, out + (size_t)TBN, I, Zb);
}

__global__ __launch_bounds__(256) void scan_inp(float* out, __hip_bfloat16* Zb) {
  scan_body(out, out + (size_t)TBN, out + (size_t)TBN, Zb);  // I staged in vs region
}

// ---------------------------------------------------------------- kernel 4
// bf16 MFMA GEMM (m97 structure): Y[8192][2048] = Z[8192][2048] @ W[2048][2048]
// A = Z row-major bf16; B = Wt (W transposed) row-major bf16 so B-fragments
// are contiguous. 128x128 tile, BK=32, 4 waves (2x2), 16x16x32 MFMA.
__global__ __launch_bounds__(256) void bern_gemm(const __hip_bfloat16* __restrict__ Z,
                                                 const __hip_bfloat16* __restrict__ Wt,
                                                 float* __restrict__ Y) {
  __shared__ __align__(16) __hip_bfloat16 Asm[128 * 32];
  __shared__ __align__(16) __hip_bfloat16 Bsm[128 * 32];
  const int tid = threadIdx.x;
  const int lane = tid & 63;
  const int wid = tid >> 6;
  const int wr = wid >> 1, wc = wid & 1;
  const int m0 = blockIdx.x * 128, n0 = blockIdx.y * 128;

  fx4 acc[4][4] = {};

  const int trow = tid >> 2;
  const int tcol = (tid & 3) << 4;
  const char* gA = (const char*)Z + ((size_t)(m0 + trow) << 12) + tcol;
  const char* gB = (const char*)Wt + ((size_t)(n0 + trow) << 12) + tcol;
  char* lA = (char*)Asm + tid * 16;
  char* lB = (char*)Bsm + tid * 16;

  const ix4* Au = (const ix4*)Asm;  // 16B units; row = 4 units
  const ix4* Bu = (const ix4*)Bsm;
  const int abase = (wr * 64 + (lane & 15)) * 4 + (lane >> 4);
  const int bbase = (wc * 64 + (lane & 15)) * 4 + (lane >> 4);

  for (int ks = 0; ks < 64; ++ks) {
    gll16(gA, lA);
    gll16(gA + (size_t)64 * 4096, lA + 4096);
    gll16(gB, lB);
    gll16(gB + (size_t)64 * 4096, lB + 4096);
    gA += 64;  // advance 32 bf16 in k
    gB += 64;
    __syncthreads();

    ix4 af[4], bf[4];
#pragma unroll
    for (int i = 0; i < 4; ++i) af[i] = Au[abase + i * 64];
#pragma unroll
    for (int i = 0; i < 4; ++i) bf[i] = Bu[bbase + i * 64];
#pragma unroll
    for (int mf = 0; mf < 4; ++mf)
#pragma unroll
      for (int nf = 0; nf < 4; ++nf)
        mfma16(acc[mf][nf], af[mf], bf[nf]);
    __syncthreads();
  }

  asm volatile("s_nop 7\n\ts_nop 7");

  // C/D layout: col = lane&15, row = (lane>>4)*4 + reg  (m89-verified)
  const int crow = (lane >> 4) * 4;
  const int ccol = lane & 15;
#pragma unroll
  for (int mf = 0; mf < 4; ++mf)
#pragma unroll
    for (int nf = 0; nf < 4; ++nf)
#pragma unroll
      for (int j = 0; j < 4; ++j) {
        const int r = m0 + wr * 64 + mf * 16 + crow + j;
        const int c = n0 + wc * 64 + nf * 16 + ccol;
        Y[(size_t)r * NN + c] = acc[mf][nf][j];
      }
}

// ---------------------------------------------------------------- kernel 5
__global__ __launch_bounds__(256) void gather_k(float* __restrict__ Y,
                                                const int* __restrict__ ridx) {
  __shared__ __align__(16) float rowbuf[NN];
  const int tb = blockIdx.x;      // 0..8191
  const int t = tb >> 5;
  float* yrow = Y + (size_t)tb * NN;
  const int tid = threadIdx.x;
#pragma unroll
  for (int i = 0; i < 2; ++i) {
    int u = tid + i * 256;
    ((fx4*)rowbuf)[u] = ((const fx4*)yrow)[u];
  }
  __syncthreads();
  const int* ir = ridx + t * NN;
#pragma unroll
  for (int i = 0; i < 8; ++i) {
    int j = tid + i * 256;
    yrow[j] = rowbuf[ir[j]];
  }
}

// ---------------------------------------------------------------- launcher
extern "C" void kernel_launch(void* const* d_in, const int* in_sizes, int n_in,
                              void* d_out, int out_size, void* d_ws, size_t ws_size,
                              hipStream_t stream) {
  const float* x      = (const float*)d_in[0];
  const float* W_in   = (const float*)d_in[1];
  const float* bias   = (const float*)d_in[2];
  const float* W_bern = (const float*)d_in[3];
  const int*   ridx   = (const int*)d_in[4];
  float* out = (float*)d_out;
  char* ws = (char*)d_ws;

  __hip_bfloat16* Wt = (__hip_bfloat16*)ws;                       // 8,388,608 B
  __hip_bfloat16* Zb = (__hip_bfloat16*)(ws + (size_t)8388608);   // 33,554,432 B
  const size_t offI = 41943040;                                   // I: 67,108,864 B
  const bool sep = ws_size >= (size_t)109051904;
  float* Ibuf = sep ? (float*)(ws + offI) : (out + (size_t)TBN);

  // Xt borrows the zs output region (2M floats); scan overwrites it later.
  float* Xt = out;

  xt_k<<<dim3(256, 8), dim3(32, 8), 0, stream>>>(x, Xt);
  wt_convert<<<dim3(64, 64), dim3(32, 8), 0, stream>>>(W_bern, Wt);
  in_gemm<<<dim3(64, 16), dim3(256), 0, stream>>>(Xt, W_in, bias, Ibuf);
  if (sep)
    scan_sep<<<dim3(256), dim3(256), 0, stream>>>(out, Ibuf, Zb);
  else
    scan_inp<<<dim3(256), dim3(256), 0, stream>>>(out, Zb);
  bern_gemm<<<dim3(64, 16), dim3(256), 0, stream>>>(Zb, Wt, out + (size_t)2 * TBN);
  gather_k<<<dim3(8192), dim3(256), 0, stream>>>(out + (size_t)2 * TBN, ridx);
}

// Round 4
// 253.025 us; speedup vs baseline: 1.2066x; 1.2066x over previous
//
#include <hip/hip_runtime.h>
#include <hip/hip_bf16.h>
#include <stdint.h>

// RSNN: T=256 steps, B=32, N_IN=256, N=2048.
// out = [3, T, B, N] fp32: zs | vs | z2s  (TBN elements each)
//
// Pipeline (all on `stream`, stream-ordered):
//   0. xt_k:       X fp32 [M][K] -> Xt [K][M]  (borrows zs out-region, pre-scan)
//   1. wt_convert: W_bern fp32 [k][n] -> Wt bf16 [n][k]   (ws +0, 8 MB)
//   2. in_gemm:    I = x @ W_in + b  (fp32, M=8192,K=256,N=2048) -> Ibuf
//                  64x128 tile, 4x8 micro, 8 blocks/CU (TLP-first; latency-bound op)
//   3. scan:       per-neuron serial v scan; writes zs, vs (fp32) and Z bf16 (ws +8MB)
//   4. bern_gemm:  Y = Z @ W_bern  (bf16 MFMA, M=8192,N=2048,K=2048) -> z2 region
//   5. gather_k:   z2[t,b,j] = Y[t,b,idx[t,j]]  in place (row via LDS)

#define T_STEPS 256
#define BATCH   32
#define NIN     256
#define NN      2048
#define BN_FLAT (BATCH * NN)            // 65536
#define TBN     (T_STEPS * BATCH * NN)  // 16777216
#define MROWS   (T_STEPS * BATCH)       // 8192

typedef __attribute__((ext_vector_type(4))) float fx4;
typedef __attribute__((ext_vector_type(4))) int   ix4;

__device__ __forceinline__ void gll16(const void* g, void* l) {
  typedef __attribute__((address_space(1))) void gvoid_t;
  typedef __attribute__((address_space(3))) void lvoid_t;
  __builtin_amdgcn_global_load_lds((gvoid_t*)(g), (lvoid_t*)(l), 16, 0, 0);
}

__device__ __forceinline__ void mfma16(fx4& d, ix4 a, ix4 b) {
  asm volatile("v_mfma_f32_16x16x32_bf16 %0, %1, %2, %0" : "+v"(d) : "v"(a), "v"(b));
}

// ---------------------------------------------------------------- kernel 0
// X [8192][256] -> Xt [256][8192]
__global__ __launch_bounds__(256) void xt_k(const float* __restrict__ X,
                                            float* __restrict__ Xt) {
  __shared__ float tile[32][33];
  const int m0 = blockIdx.x << 5, k0 = blockIdx.y << 5;
  const int tx = threadIdx.x, ty = threadIdx.y;
#pragma unroll
  for (int i = 0; i < 32; i += 8)
    tile[ty + i][tx] = X[(size_t)(m0 + ty + i) * NIN + k0 + tx];
  __syncthreads();
#pragma unroll
  for (int i = 0; i < 32; i += 8)
    Xt[(size_t)(k0 + ty + i) * MROWS + m0 + tx] = tile[tx][ty + i];
}

// ---------------------------------------------------------------- kernel 1
__global__ __launch_bounds__(256) void wt_convert(const float* __restrict__ W,
                                                  __hip_bfloat16* __restrict__ Wt) {
  __shared__ float tile[32][33];
  const int k0 = blockIdx.y << 5, n0 = blockIdx.x << 5;
  const int tx = threadIdx.x, ty = threadIdx.y;
#pragma unroll
  for (int i = 0; i < 32; i += 8)
    tile[ty + i][tx] = W[(size_t)(k0 + ty + i) * NN + n0 + tx];
  __syncthreads();
#pragma unroll
  for (int i = 0; i < 32; i += 8)
    Wt[(size_t)(n0 + ty + i) * NN + k0 + tx] = __float2bfloat16(tile[tx][ty + i]);
}

// ---------------------------------------------------------------- kernel 2
// fp32 GEMM: I[8192][2048] = Xt^T @ Wi + bias.
// TLP-first design: 64x128 tile, 256 threads, 4x8 micro (cols split 4+4 at
// +64), BK=16, grid 2048 blocks = 8 blocks/CU = 32 waves/CU. Staging is
// 3x global_load_lds (no VALU cost); single-buffer + __syncthreads -- the
// vmcnt drain is hidden by the 7 other resident blocks (m114 wave overlap).
// LDS reads: a = 4 addrs/wave 16-way bcast (free), b = 16x16B contiguous
// (conflict-free). Low VGPR (~60) so occupancy is grid-capped, not reg-capped.
__global__ __launch_bounds__(256) void in_gemm(const float* __restrict__ Xt,
                                               const float* __restrict__ Wi,
                                               const float* __restrict__ bias,
                                               float* __restrict__ I) {
  __shared__ __align__(16) float As[16 * 64];   // [k][m] 4 KB
  __shared__ __align__(16) float Bs[16 * 128];  // [k][n] 8 KB
  const int tid = threadIdx.x;
  const int tm = tid >> 4;   // 0..15 -> rows tm*4..+3
  const int tn = tid & 15;   // 0..15 -> cols {tn*4..+3} u {64+tn*4..+3}
  const int m0 = blockIdx.x * 64, n0 = blockIdx.y * 128;

  fx4 acc[4][2] = {};

  // staging: A unit u = tid: k=u>>4, m4=(u&15)*4.  B unit u = tid + j*256:
  // k = u>>5, n4 = (u&31)*4.  LDS dest linear at u*16 bytes.
  const float* gA = Xt + (size_t)(tid >> 4) * MROWS + m0 + (tid & 15) * 4;
  const float* gB = Wi + (size_t)(tid >> 5) * NN + n0 + (tid & 31) * 4;
  char* lA = (char*)As + tid * 16;
  char* lB = (char*)Bs + tid * 16;

  for (int k0 = 0; k0 < NIN; k0 += 16) {
    gll16(gA, lA);
    gll16(gB, lB);
    gll16(gB + 8 * NN, lB + 4096);
    gA += (size_t)16 * MROWS;
    gB += (size_t)16 * NN;
    __syncthreads();  // drains vmcnt; hidden by other resident blocks
#pragma unroll
    for (int kk = 0; kk < 16; ++kk) {
      fx4 a  = *(const fx4*)&As[kk * 64 + tm * 4];
      fx4 b0 = *(const fx4*)&Bs[kk * 128 + tn * 4];
      fx4 b1 = *(const fx4*)&Bs[kk * 128 + 64 + tn * 4];
#pragma unroll
      for (int r = 0; r < 4; ++r)
#pragma unroll
        for (int c = 0; c < 4; ++c) {
          acc[r][0][c] = fmaf(a[r], b0[c], acc[r][0][c]);
          acc[r][1][c] = fmaf(a[r], b1[c], acc[r][1][c]);
        }
    }
    __syncthreads();
  }

#pragma unroll
  for (int r = 0; r < 4; ++r) {
    const size_t row = (size_t)(m0 + tm * 4 + r) * NN;
    fx4 r0, r1;
#pragma unroll
    for (int c = 0; c < 4; ++c) {
      r0[c] = acc[r][0][c] + bias[n0 + tn * 4 + c];
      r1[c] = acc[r][1][c] + bias[n0 + 64 + tn * 4 + c];
    }
    *(fx4*)&I[row + n0 + tn * 4] = r0;
    *(fx4*)&I[row + n0 + 64 + tn * 4] = r1;
  }
}

// ---------------------------------------------------------------- kernel 3
// Per-neuron serial scan over t. One thread per (b,n). Prefetch-unrolled x8.
// Matches numpy elementwise semantics: decay*v computed with separate
// mul+add (no fma contraction) so rounding matches the reference closely.
__device__ __forceinline__ void scan_body(float* zs, float* vsout,
                                          const float* I, __hip_bfloat16* Zb) {
  const int nid = blockIdx.x * 256 + threadIdx.x;  // 0..65535
  float v = 0.f;
  for (int t0 = 0; t0 < T_STEPS; t0 += 8) {
    float iin[8];
#pragma unroll
    for (int u = 0; u < 8; ++u)
      iin[u] = I[(size_t)(t0 + u) * BN_FLAT + nid];
#pragma unroll
    for (int u = 0; u < 8; ++u) {
      float nv = __fadd_rn(__fmul_rn(0.9048374180359595f, v), iin[u]);
      nv = fminf(fmaxf(nv, -1.0f), 1.01f);
      const bool sp = nv > 1.0f;        // == (new_v - THR) > 0 in fp32
      const float z = sp ? 1.0f : 0.0f;
      nv = sp ? -1.0f : nv;             // hard reset
      const size_t off = (size_t)(t0 + u) * BN_FLAT + nid;
      zs[off] = z;
      vsout[off] = nv;
      Zb[off] = __float2bfloat16(z);    // exact 0/1
      v = nv;
    }
  }
}

__global__ __launch_bounds__(256) void scan_sep(float* __restrict__ out,
                                                const float* __restrict__ I,
                                                __hip_bfloat16* __restrict__ Zb) {
  scan_body(out, out + (size_t)TBN, I, Zb);
}

__global__ __launch_bounds__(256) void scan_inp(float* out, __hip_bfloat16* Zb) {
  scan_body(out, out + (size_t)TBN, out + (size_t)TBN, Zb);  // I staged in vs region
}

// ---------------------------------------------------------------- kernel 4
// bf16 MFMA GEMM (m97 structure): Y[8192][2048] = Z[8192][2048] @ W[2048][2048]
// A = Z row-major bf16; B = Wt (W transposed) row-major bf16 so B-fragments
// are contiguous. 128x128 tile, BK=32, 4 waves (2x2), 16x16x32 MFMA.
__global__ __launch_bounds__(256) void bern_gemm(const __hip_bfloat16* __restrict__ Z,
                                                 const __hip_bfloat16* __restrict__ Wt,
                                                 float* __restrict__ Y) {
  __shared__ __align__(16) __hip_bfloat16 Asm[128 * 32];
  __shared__ __align__(16) __hip_bfloat16 Bsm[128 * 32];
  const int tid = threadIdx.x;
  const int lane = tid & 63;
  const int wid = tid >> 6;
  const int wr = wid >> 1, wc = wid & 1;
  const int m0 = blockIdx.x * 128, n0 = blockIdx.y * 128;

  fx4 acc[4][4] = {};

  const int trow = tid >> 2;
  const int tcol = (tid & 3) << 4;
  const char* gA = (const char*)Z + ((size_t)(m0 + trow) << 12) + tcol;
  const char* gB = (const char*)Wt + ((size_t)(n0 + trow) << 12) + tcol;
  char* lA = (char*)Asm + tid * 16;
  char* lB = (char*)Bsm + tid * 16;

  const ix4* Au = (const ix4*)Asm;  // 16B units; row = 4 units
  const ix4* Bu = (const ix4*)Bsm;
  const int abase = (wr * 64 + (lane & 15)) * 4 + (lane >> 4);
  const int bbase = (wc * 64 + (lane & 15)) * 4 + (lane >> 4);

  for (int ks = 0; ks < 64; ++ks) {
    gll16(gA, lA);
    gll16(gA + (size_t)64 * 4096, lA + 4096);
    gll16(gB, lB);
    gll16(gB + (size_t)64 * 4096, lB + 4096);
    gA += 64;  // advance 32 bf16 in k
    gB += 64;
    __syncthreads();

    ix4 af[4], bf[4];
#pragma unroll
    for (int i = 0; i < 4; ++i) af[i] = Au[abase + i * 64];
#pragma unroll
    for (int i = 0; i < 4; ++i) bf[i] = Bu[bbase + i * 64];
#pragma unroll
    for (int mf = 0; mf < 4; ++mf)
#pragma unroll
      for (int nf = 0; nf < 4; ++nf)
        mfma16(acc[mf][nf], af[mf], bf[nf]);
    __syncthreads();
  }

  asm volatile("s_nop 7\n\ts_nop 7");

  // C/D layout: col = lane&15, row = (lane>>4)*4 + reg  (m89-verified)
  const int crow = (lane >> 4) * 4;
  const int ccol = lane & 15;
#pragma unroll
  for (int mf = 0; mf < 4; ++mf)
#pragma unroll
    for (int nf = 0; nf < 4; ++nf)
#pragma unroll
      for (int j = 0; j < 4; ++j) {
        const int r = m0 + wr * 64 + mf * 16 + crow + j;
        const int c = n0 + wc * 64 + nf * 16 + ccol;
        Y[(size_t)r * NN + c] = acc[mf][nf][j];
      }
}

// ---------------------------------------------------------------- kernel 5
__global__ __launch_bounds__(256) void gather_k(float* __restrict__ Y,
                                                const int* __restrict__ ridx) {
  __shared__ __align__(16) float rowbuf[NN];
  const int tb = blockIdx.x;      // 0..8191
  const int t = tb >> 5;
  float* yrow = Y + (size_t)tb * NN;
  const int tid = threadIdx.x;
#pragma unroll
  for (int i = 0; i < 2; ++i) {
    int u = tid + i * 256;
    ((fx4*)rowbuf)[u] = ((const fx4*)yrow)[u];
  }
  __syncthreads();
  const int* ir = ridx + t * NN;
#pragma unroll
  for (int i = 0; i < 8; ++i) {
    int j = tid + i * 256;
    yrow[j] = rowbuf[ir[j]];
  }
}

// ---------------------------------------------------------------- launcher
extern "C" void kernel_launch(void* const* d_in, const int* in_sizes, int n_in,
                              void* d_out, int out_size, void* d_ws, size_t ws_size,
                              hipStream_t stream) {
  const float* x      = (const float*)d_in[0];
  const float* W_in   = (const float*)d_in[1];
  const float* bias   = (const float*)d_in[2];
  const float* W_bern = (const float*)d_in[3];
  const int*   ridx   = (const int*)d_in[4];
  float* out = (float*)d_out;
  char* ws = (char*)d_ws;

  __hip_bfloat16* Wt = (__hip_bfloat16*)ws;                       // 8,388,608 B
  __hip_bfloat16* Zb = (__hip_bfloat16*)(ws + (size_t)8388608);   // 33,554,432 B
  const size_t offI = 41943040;                                   // I: 67,108,864 B
  const bool sep = ws_size >= (size_t)109051904;
  float* Ibuf = sep ? (float*)(ws + offI) : (out + (size_t)TBN);

  // Xt borrows the zs output region (2M floats); scan overwrites it later.
  float* Xt = out;

  xt_k<<<dim3(256, 8), dim3(32, 8), 0, stream>>>(x, Xt);
  wt_convert<<<dim3(64, 64), dim3(32, 8), 0, stream>>>(W_bern, Wt);
  in_gemm<<<dim3(128, 16), dim3(256), 0, stream>>>(Xt, W_in, bias, Ibuf);
  if (sep)
    scan_sep<<<dim3(256), dim3(256), 0, stream>>>(out, Ibuf, Zb);
  else
    scan_inp<<<dim3(256), dim3(256), 0, stream>>>(out, Zb);
  bern_gemm<<<dim3(64, 16), dim3(256), 0, stream>>>(Zb, Wt, out + (size_t)2 * TBN);
  gather_k<<<dim3(8192), dim3(256), 0, stream>>>(out + (size_t)2 * TBN, ridx);
}

// Round 5
// 238.426 us; speedup vs baseline: 1.2804x; 1.0612x over previous
//
#include <hip/hip_runtime.h>
#include <hip/hip_bf16.h>
#include <stdint.h>

// RSNN: T=256 steps, B=32, N_IN=256, N=2048.
// out = [3, T, B, N] fp32: zs | vs | z2s  (TBN elements each)
//
// Pipeline (all on `stream`, stream-ordered):
//   0. xt_k:       X fp32 [M][K] -> Xt [K][M]  (borrows zs out-region, pre-scan)
//   1. wt_convert: W_bern fp32 [k][n] -> Wt bf16 [n][k]   (ws +0, 8 MB)
//   2. in_gemm:    I = x @ W_in + b  (fp32) - 64x128 tile, TLP-first (R4 winner)
//   3. scan:       per-neuron serial v scan; writes zs, vs (fp32) and Z bf16
//   4. bern_gemm:  Y = Z @ W_bern  -- 256^2 8-phase bf16 MFMA template
//                  (T2 XOR-swizzle + T3/T4 counted vmcnt + T5 setprio)
//   5. gather_k:   z2[t,b,j] = Y[t,b,idx[t,j]]  in place (row via LDS)

#define T_STEPS 256
#define BATCH   32
#define NIN     256
#define NN      2048
#define BN_FLAT (BATCH * NN)            // 65536
#define TBN     (T_STEPS * BATCH * NN)  // 16777216
#define MROWS   (T_STEPS * BATCH)       // 8192

typedef __attribute__((ext_vector_type(4))) float fx4;
typedef __attribute__((ext_vector_type(4))) int   ix4;

__device__ __forceinline__ void gll16(const void* g, void* l) {
  typedef __attribute__((address_space(1))) void gvoid_t;
  typedef __attribute__((address_space(3))) void lvoid_t;
  __builtin_amdgcn_global_load_lds((gvoid_t*)(g), (lvoid_t*)(l), 16, 0, 0);
}

__device__ __forceinline__ void mfma16(fx4& d, ix4 a, ix4 b) {
  asm volatile("v_mfma_f32_16x16x32_bf16 %0, %1, %2, %0" : "+v"(d) : "v"(a), "v"(b));
}

// ---------------------------------------------------------------- kernel 0
// X [8192][256] -> Xt [256][8192]
__global__ __launch_bounds__(256) void xt_k(const float* __restrict__ X,
                                            float* __restrict__ Xt) {
  __shared__ float tile[32][33];
  const int m0 = blockIdx.x << 5, k0 = blockIdx.y << 5;
  const int tx = threadIdx.x, ty = threadIdx.y;
#pragma unroll
  for (int i = 0; i < 32; i += 8)
    tile[ty + i][tx] = X[(size_t)(m0 + ty + i) * NIN + k0 + tx];
  __syncthreads();
#pragma unroll
  for (int i = 0; i < 32; i += 8)
    Xt[(size_t)(k0 + ty + i) * MROWS + m0 + tx] = tile[tx][ty + i];
}

// ---------------------------------------------------------------- kernel 1
__global__ __launch_bounds__(256) void wt_convert(const float* __restrict__ W,
                                                  __hip_bfloat16* __restrict__ Wt) {
  __shared__ float tile[32][33];
  const int k0 = blockIdx.y << 5, n0 = blockIdx.x << 5;
  const int tx = threadIdx.x, ty = threadIdx.y;
#pragma unroll
  for (int i = 0; i < 32; i += 8)
    tile[ty + i][tx] = W[(size_t)(k0 + ty + i) * NN + n0 + tx];
  __syncthreads();
#pragma unroll
  for (int i = 0; i < 32; i += 8)
    Wt[(size_t)(n0 + ty + i) * NN + k0 + tx] = __float2bfloat16(tile[tx][ty + i]);
}

// ---------------------------------------------------------------- kernel 2
// fp32 GEMM: I[8192][2048] = Xt^T @ Wi + bias.  (R4 structure, unchanged)
__global__ __launch_bounds__(256) void in_gemm(const float* __restrict__ Xt,
                                               const float* __restrict__ Wi,
                                               const float* __restrict__ bias,
                                               float* __restrict__ I) {
  __shared__ __align__(16) float As[16 * 64];   // [k][m] 4 KB
  __shared__ __align__(16) float Bs[16 * 128];  // [k][n] 8 KB
  const int tid = threadIdx.x;
  const int tm = tid >> 4;
  const int tn = tid & 15;
  const int m0 = blockIdx.x * 64, n0 = blockIdx.y * 128;

  fx4 acc[4][2] = {};

  const float* gA = Xt + (size_t)(tid >> 4) * MROWS + m0 + (tid & 15) * 4;
  const float* gB = Wi + (size_t)(tid >> 5) * NN + n0 + (tid & 31) * 4;
  char* lA = (char*)As + tid * 16;
  char* lB = (char*)Bs + tid * 16;

  for (int k0 = 0; k0 < NIN; k0 += 16) {
    gll16(gA, lA);
    gll16(gB, lB);
    gll16(gB + 8 * NN, lB + 4096);
    gA += (size_t)16 * MROWS;
    gB += (size_t)16 * NN;
    __syncthreads();
#pragma unroll
    for (int kk = 0; kk < 16; ++kk) {
      fx4 a  = *(const fx4*)&As[kk * 64 + tm * 4];
      fx4 b0 = *(const fx4*)&Bs[kk * 128 + tn * 4];
      fx4 b1 = *(const fx4*)&Bs[kk * 128 + 64 + tn * 4];
#pragma unroll
      for (int r = 0; r < 4; ++r)
#pragma unroll
        for (int c = 0; c < 4; ++c) {
          acc[r][0][c] = fmaf(a[r], b0[c], acc[r][0][c]);
          acc[r][1][c] = fmaf(a[r], b1[c], acc[r][1][c]);
        }
    }
    __syncthreads();
  }

#pragma unroll
  for (int r = 0; r < 4; ++r) {
    const size_t row = (size_t)(m0 + tm * 4 + r) * NN;
    fx4 r0, r1;
#pragma unroll
    for (int c = 0; c < 4; ++c) {
      r0[c] = acc[r][0][c] + bias[n0 + tn * 4 + c];
      r1[c] = acc[r][1][c] + bias[n0 + 64 + tn * 4 + c];
    }
    *(fx4*)&I[row + n0 + tn * 4] = r0;
    *(fx4*)&I[row + n0 + 64 + tn * 4] = r1;
  }
}

// ---------------------------------------------------------------- kernel 3
__device__ __forceinline__ void scan_body(float* zs, float* vsout,
                                          const float* I, __hip_bfloat16* Zb) {
  const int nid = blockIdx.x * 256 + threadIdx.x;  // 0..65535
  float v = 0.f;
  for (int t0 = 0; t0 < T_STEPS; t0 += 8) {
    float iin[8];
#pragma unroll
    for (int u = 0; u < 8; ++u)
      iin[u] = I[(size_t)(t0 + u) * BN_FLAT + nid];
#pragma unroll
    for (int u = 0; u < 8; ++u) {
      float nv = __fadd_rn(__fmul_rn(0.9048374180359595f, v), iin[u]);
      nv = fminf(fmaxf(nv, -1.0f), 1.01f);
      const bool sp = nv > 1.0f;
      const float z = sp ? 1.0f : 0.0f;
      nv = sp ? -1.0f : nv;
      const size_t off = (size_t)(t0 + u) * BN_FLAT + nid;
      zs[off] = z;
      vsout[off] = nv;
      Zb[off] = __float2bfloat16(z);
      v = nv;
    }
  }
}

__global__ __launch_bounds__(256) void scan_sep(float* __restrict__ out,
                                                const float* __restrict__ I,
                                                __hip_bfloat16* __restrict__ Zb) {
  scan_body(out, out + (size_t)TBN, I, Zb);
}

__global__ __launch_bounds__(256) void scan_inp(float* out, __hip_bfloat16* Zb) {
  scan_body(out, out + (size_t)TBN, out + (size_t)TBN, Zb);
}

// ---------------------------------------------------------------- kernel 4
// 256x256 8-phase bf16 MFMA GEMM: Y[8192][2048] = Z[8192][2048] @ Wt^T.
// BK=64, 8 waves (2M x 4N), 512 thr, LDS 128 KiB (2 dbuf x 2 half x A,B).
// Per wave: 128x64 output = 8x4 16x16 frags, 64 MFMA/K-tile over 4 phases.
// T2: XOR swizzle byte^=((row&7)<<4); gll16 dest linear, global src
//     pre-swizzled with the same involution (both-sides rule).
// T3/T4: per phase stage 1 half-tile; vmcnt(4) once per K-tile (2 halves
//     = 4 loads always in flight across the wait; never drain in-loop).
// T5: setprio(1) around each 16-MFMA cluster.
// Stage lifetimes: A(t+1) staged ph1/ph2 (writes other buf); B(t+2) staged
// ph3/ph4 (same buf as t, but B-reads of tile t end at ph2's barrier).
__global__ __launch_bounds__(512, 2) void bern_gemm(const __hip_bfloat16* __restrict__ Z,
                                                    const __hip_bfloat16* __restrict__ Wt,
                                                    float* __restrict__ Y) {
  __shared__ __align__(16) char lds[131072];
  const int tid = threadIdx.x;
  const int l = tid & 63, wid = tid >> 6;
  const int wr = wid >> 2, wc = wid & 3;       // 2 x 4 wave grid
  const int l15 = l & 15, l4 = l >> 4;
  const int swz = (l & 7) << 4;                // lane-constant row-XOR
  const int colp[2] = { (l4 * 16) ^ swz, (64 + l4 * 16) ^ swz };
  const int m0 = blockIdx.x * 256, n0 = blockIdx.y * 256;
  const int aoff = wr * 16384 + l15 * 128;                          // A: half=wr
  const int boff = 65536 + (wc >> 1) * 16384 + ((wc & 1) * 64 + l15) * 128;
  // staging: unit u covers row u>>3, 16B col ((u&7)^((u>>3)&7))*16 (inverse swz)
  const int colsel = ((tid & 7) ^ ((tid >> 3) & 7)) * 16;
  const char* gA_ = (const char*)Z + ((size_t)(m0 + (tid >> 3)) << 12) + colsel;
  const char* gB_ = (const char*)Wt + ((size_t)(n0 + (tid >> 3)) << 12) + colsel;

  fx4 acc[8][4] = {};
  ix4 af[4][2], bf[4][2];

#define STAGE_A(tt, h)                                                       \
  do {                                                                       \
    const char* g = gA_ + ((size_t)((h) * 128) << 12) + (size_t)(tt) * 128;  \
    char* d = lds + (((tt) & 1) * 32768) + (h) * 16384 + tid * 16;           \
    gll16(g, d);                                                             \
    gll16(g + ((size_t)64 << 12), d + 8192);                                 \
  } while (0)
#define STAGE_B(tt, h)                                                       \
  do {                                                                       \
    const char* g = gB_ + ((size_t)((h) * 128) << 12) + (size_t)(tt) * 128;  \
    char* d = lds + 65536 + (((tt) & 1) * 32768) + (h) * 16384 + tid * 16;   \
    gll16(g, d);                                                             \
    gll16(g + ((size_t)64 << 12), d + 8192);                                 \
  } while (0)
#define LDA(mh)                                                              \
  _Pragma("unroll") for (int mf = 0; mf < 4; ++mf)                           \
    _Pragma("unroll") for (int ks = 0; ks < 2; ++ks)                         \
      af[mf][ks] = *(const ix4*)(lb + aoff + ((mh)*4 + mf) * 2048 + colp[ks]);
#define LDB(nh)                                                              \
  _Pragma("unroll") for (int nf = 0; nf < 2; ++nf)                           \
    _Pragma("unroll") for (int ks = 0; ks < 2; ++ks)                         \
      bf[(nh)*2 + nf][ks] = *(const ix4*)(lb + boff + ((nh)*2 + nf) * 2048 + colp[ks]);
#define MFMA_QUAD(mh, nh)                                                    \
  do {                                                                       \
    __builtin_amdgcn_s_setprio(1);                                           \
    _Pragma("unroll") for (int ks = 0; ks < 2; ++ks)                         \
      _Pragma("unroll") for (int mf = 0; mf < 4; ++mf)                       \
        _Pragma("unroll") for (int nf = 0; nf < 2; ++nf)                     \
          mfma16(acc[(mh)*4 + mf][(nh)*2 + nf], af[mf][ks], bf[(nh)*2 + nf][ks]); \
    __builtin_amdgcn_s_setprio(0);                                           \
  } while (0)
#define SBAR asm volatile("s_barrier" ::: "memory")

  // prologue: tile0 (A+B) + B(1); tile0's 8 loads done, B(1)'s 4 in flight
  STAGE_A(0, 0); STAGE_A(0, 1); STAGE_B(0, 0); STAGE_B(0, 1);
  STAGE_B(1, 0); STAGE_B(1, 1);
  asm volatile("s_waitcnt vmcnt(4)" ::: "memory");
  SBAR;

  for (int t = 0; t < 32; ++t) {
    const char* lb = lds + (t & 1) * 32768;
    // ---- phase 1: A[mh0] + B[nh0] reads; stage A(t+1)h0
    LDA(0); LDB(0);
    if (t < 31) STAGE_A(t + 1, 0);
    SBAR;
    asm volatile("s_waitcnt lgkmcnt(0)" ::: "memory");
    MFMA_QUAD(0, 0);
    SBAR;
    // ---- phase 2: B[nh1] reads; stage A(t+1)h1
    LDB(1);
    if (t < 31) STAGE_A(t + 1, 1);
    SBAR;
    asm volatile("s_waitcnt lgkmcnt(0)" ::: "memory");
    MFMA_QUAD(0, 1);
    SBAR;
    // ---- phase 3: A[mh1] reads; stage B(t+2)h0 (B(t) reads done at ph2 bar)
    LDA(1);
    if (t < 30) STAGE_B(t + 2, 0);
    SBAR;
    asm volatile("s_waitcnt lgkmcnt(0)" ::: "memory");
    MFMA_QUAD(1, 0);
    SBAR;
    // ---- phase 4: no reads; stage B(t+2)h1; counted vmcnt (4 = B(t+2) pair)
    if (t < 30) STAGE_B(t + 2, 1);
    SBAR;
    MFMA_QUAD(1, 1);
    if (t < 30) asm volatile("s_waitcnt vmcnt(4)" ::: "memory");
    else        asm volatile("s_waitcnt vmcnt(0)" ::: "memory");
    SBAR;
  }

#undef STAGE_A
#undef STAGE_B
#undef LDA
#undef LDB
#undef MFMA_QUAD
#undef SBAR

  // C/D layout: col = lane&15, row = (lane>>4)*4 + reg  (m89-verified)
  const int crow = l4 * 4;
#pragma unroll
  for (int MF = 0; MF < 8; ++MF)
#pragma unroll
    for (int NF = 0; NF < 4; ++NF)
#pragma unroll
      for (int j = 0; j < 4; ++j) {
        const int r = m0 + wr * 128 + MF * 16 + crow + j;
        const int c = n0 + wc * 64 + NF * 16 + l15;
        Y[(size_t)r * NN + c] = acc[MF][NF][j];
      }
}

// ---------------------------------------------------------------- kernel 5
__global__ __launch_bounds__(256) void gather_k(float* __restrict__ Y,
                                                const int* __restrict__ ridx) {
  __shared__ __align__(16) float rowbuf[NN];
  const int tb = blockIdx.x;      // 0..8191
  const int t = tb >> 5;
  float* yrow = Y + (size_t)tb * NN;
  const int tid = threadIdx.x;
#pragma unroll
  for (int i = 0; i < 2; ++i) {
    int u = tid + i * 256;
    ((fx4*)rowbuf)[u] = ((const fx4*)yrow)[u];
  }
  __syncthreads();
  const int* ir = ridx + t * NN;
#pragma unroll
  for (int i = 0; i < 8; ++i) {
    int j = tid + i * 256;
    yrow[j] = rowbuf[ir[j]];
  }
}

// ---------------------------------------------------------------- launcher
extern "C" void kernel_launch(void* const* d_in, const int* in_sizes, int n_in,
                              void* d_out, int out_size, void* d_ws, size_t ws_size,
                              hipStream_t stream) {
  const float* x      = (const float*)d_in[0];
  const float* W_in   = (const float*)d_in[1];
  const float* bias   = (const float*)d_in[2];
  const float* W_bern = (const float*)d_in[3];
  const int*   ridx   = (const int*)d_in[4];
  float* out = (float*)d_out;
  char* ws = (char*)d_ws;

  __hip_bfloat16* Wt = (__hip_bfloat16*)ws;                       // 8,388,608 B
  __hip_bfloat16* Zb = (__hip_bfloat16*)(ws + (size_t)8388608);   // 33,554,432 B
  const size_t offI = 41943040;                                   // I: 67,108,864 B
  const bool sep = ws_size >= (size_t)109051904;
  float* Ibuf = sep ? (float*)(ws + offI) : (out + (size_t)TBN);

  // Xt borrows the zs output region (2M floats); scan overwrites it later.
  float* Xt = out;

  xt_k<<<dim3(256, 8), dim3(32, 8), 0, stream>>>(x, Xt);
  wt_convert<<<dim3(64, 64), dim3(32, 8), 0, stream>>>(W_bern, Wt);
  in_gemm<<<dim3(128, 16), dim3(256), 0, stream>>>(Xt, W_in, bias, Ibuf);
  if (sep)
    scan_sep<<<dim3(256), dim3(256), 0, stream>>>(out, Ibuf, Zb);
  else
    scan_inp<<<dim3(256), dim3(256), 0, stream>>>(out, Zb);
  bern_gemm<<<dim3(32, 8), dim3(512), 0, stream>>>(Zb, Wt, out + (size_t)2 * TBN);
  gather_k<<<dim3(8192), dim3(256), 0, stream>>>(out + (size_t)2 * TBN, ridx);
}

// Round 6
// 230.354 us; speedup vs baseline: 1.3253x; 1.0350x over previous
//
#include <hip/hip_runtime.h>
#include <hip/hip_bf16.h>
#include <stdint.h>

// RSNN: T=256 steps, B=32, N_IN=256, N=2048.
// out = [3, T, B, N] fp32: zs | vs | z2s  (TBN elements each)
//
// Pipeline (all on `stream`, stream-ordered):
//   1. wt_convert: W_bern fp32 [k][n] -> Wt bf16 [n][k]   (ws +0, 8 MB)
//   2. in_gemm:    I = x @ W_in + b  (fp32) -- scalar-A (SMEM) + LDS-B design:
//                  wave owns 8 rows x 256 cols; A wave-uniform via s_load,
//                  B one contiguous ds_read_b128/kk. VALU-bound by design.
//   3. scan:       per-neuron serial v scan; writes zs, vs (fp32) and Z bf16
//   4. bern_gemm:  Y = Z @ W_bern  -- 256^2 8-phase bf16 MFMA template
//                  (T2 XOR-swizzle + T3/T4 counted vmcnt + T5 setprio)
//   5. gather_k:   z2[t,b,j] = Y[t,b,idx[t,j]]  in place (row via LDS)

#define T_STEPS 256
#define BATCH   32
#define NIN     256
#define NN      2048
#define BN_FLAT (BATCH * NN)            // 65536
#define TBN     (T_STEPS * BATCH * NN)  // 16777216
#define MROWS   (T_STEPS * BATCH)       // 8192

typedef __attribute__((ext_vector_type(4))) float fx4;
typedef __attribute__((ext_vector_type(4))) int   ix4;

__device__ __forceinline__ void gll16(const void* g, void* l) {
  typedef __attribute__((address_space(1))) void gvoid_t;
  typedef __attribute__((address_space(3))) void lvoid_t;
  __builtin_amdgcn_global_load_lds((gvoid_t*)(g), (lvoid_t*)(l), 16, 0, 0);
}

__device__ __forceinline__ void mfma16(fx4& d, ix4 a, ix4 b) {
  asm volatile("v_mfma_f32_16x16x32_bf16 %0, %1, %2, %0" : "+v"(d) : "v"(a), "v"(b));
}

// ---------------------------------------------------------------- kernel 1
__global__ __launch_bounds__(256) void wt_convert(const float* __restrict__ W,
                                                  __hip_bfloat16* __restrict__ Wt) {
  __shared__ float tile[32][33];
  const int k0 = blockIdx.y << 5, n0 = blockIdx.x << 5;
  const int tx = threadIdx.x, ty = threadIdx.y;
#pragma unroll
  for (int i = 0; i < 32; i += 8)
    tile[ty + i][tx] = W[(size_t)(k0 + ty + i) * NN + n0 + tx];
  __syncthreads();
#pragma unroll
  for (int i = 0; i < 32; i += 8)
    Wt[(size_t)(n0 + ty + i) * NN + k0 + tx] = __float2bfloat16(tile[tx][ty + i]);
}

// ---------------------------------------------------------------- kernel 2
// fp32 GEMM: I[8192][2048] = X @ Wi + bias.
// Block 32 rows x 256 cols, 4 waves; wave w owns rows m0+8w..+7, lane owns
// cols n0+lane*4..+3. A (x) is wave-uniform -> readfirstlane row base ->
// s_load_dwordx4 (SMEM pipe, no LDS/VALU). B staged [16][256] via gll16,
// read as ONE contiguous conflict-free ds_read_b128 per kk.
// Per wave-kk: 32 FMA (64 VALU cyc) vs 12 LDS cyc -> VALU-bound.
// Grid 2048 blocks = 8 blocks/CU (TLP hides the vmcnt drain, m114).
__global__ __launch_bounds__(256) void in_gemm(const float* __restrict__ X,
                                               const float* __restrict__ Wi,
                                               const float* __restrict__ bias,
                                               float* __restrict__ I) {
  __shared__ __align__(16) float Bs[16 * 256];  // [k][n] 16 KB
  const int tid = threadIdx.x;
  const int lane = tid & 63;
  const int w = tid >> 6;
  const int m0 = blockIdx.x * 32, n0 = blockIdx.y * 256;
  const int wrow = __builtin_amdgcn_readfirstlane(m0 + 8 * w);
  const float* aP = X + (size_t)wrow * NIN;   // SGPR base -> scalar loads

  fx4 acc[8] = {};

  // B staging: unit u = tid + j*256: row = (u>>6), col16 = (u&63)
  const float* gB = Wi + (size_t)(tid >> 6) * NN + n0 + (tid & 63) * 4;
  char* lB = (char*)Bs + tid * 16;

  for (int k0 = 0; k0 < NIN; k0 += 16) {
#pragma unroll
    for (int j = 0; j < 4; ++j)
      gll16(gB + (size_t)(4 * j) * NN, lB + 4096 * j);
    gB += (size_t)16 * NN;
    __syncthreads();  // drains vmcnt; hidden by 7 other resident blocks
#pragma unroll
    for (int kq = 0; kq < 4; ++kq) {
      fx4 ar[8];
#pragma unroll
      for (int r = 0; r < 8; ++r)
        ar[r] = *(const fx4*)&aP[r * NIN + k0 + kq * 4];  // uniform -> s_load
#pragma unroll
      for (int kk = 0; kk < 4; ++kk) {
        fx4 b = *(const fx4*)&Bs[(kq * 4 + kk) * 256 + lane * 4];
#pragma unroll
        for (int r = 0; r < 8; ++r)
#pragma unroll
          for (int c = 0; c < 4; ++c)
            acc[r][c] = fmaf(ar[r][kk], b[c], acc[r][c]);
      }
    }
    __syncthreads();
  }

#pragma unroll
  for (int r = 0; r < 8; ++r) {
    fx4 res;
#pragma unroll
    for (int c = 0; c < 4; ++c) res[c] = acc[r][c] + bias[n0 + lane * 4 + c];
    *(fx4*)&I[(size_t)(wrow + r) * NN + n0 + lane * 4] = res;
  }
}

// ---------------------------------------------------------------- kernel 3
__device__ __forceinline__ void scan_body(float* zs, float* vsout,
                                          const float* I, __hip_bfloat16* Zb) {
  const int nid = blockIdx.x * 256 + threadIdx.x;  // 0..65535
  float v = 0.f;
  for (int t0 = 0; t0 < T_STEPS; t0 += 8) {
    float iin[8];
#pragma unroll
    for (int u = 0; u < 8; ++u)
      iin[u] = I[(size_t)(t0 + u) * BN_FLAT + nid];
#pragma unroll
    for (int u = 0; u < 8; ++u) {
      float nv = __fadd_rn(__fmul_rn(0.9048374180359595f, v), iin[u]);
      nv = fminf(fmaxf(nv, -1.0f), 1.01f);
      const bool sp = nv > 1.0f;
      const float z = sp ? 1.0f : 0.0f;
      nv = sp ? -1.0f : nv;
      const size_t off = (size_t)(t0 + u) * BN_FLAT + nid;
      zs[off] = z;
      vsout[off] = nv;
      Zb[off] = __float2bfloat16(z);
      v = nv;
    }
  }
}

__global__ __launch_bounds__(256) void scan_sep(float* __restrict__ out,
                                                const float* __restrict__ I,
                                                __hip_bfloat16* __restrict__ Zb) {
  scan_body(out, out + (size_t)TBN, I, Zb);
}

__global__ __launch_bounds__(256) void scan_inp(float* out, __hip_bfloat16* Zb) {
  scan_body(out, out + (size_t)TBN, out + (size_t)TBN, Zb);
}

// ---------------------------------------------------------------- kernel 4
// 256x256 8-phase bf16 MFMA GEMM: Y[8192][2048] = Z[8192][2048] @ Wt^T.
// (R5 winner, unchanged.) BK=64, 8 waves (2M x 4N), 512 thr, LDS 128 KiB.
// T2 XOR-swizzle both-sides; T3/T4 counted vmcnt(4); T5 setprio.
__global__ __launch_bounds__(512, 2) void bern_gemm(const __hip_bfloat16* __restrict__ Z,
                                                    const __hip_bfloat16* __restrict__ Wt,
                                                    float* __restrict__ Y) {
  __shared__ __align__(16) char lds[131072];
  const int tid = threadIdx.x;
  const int l = tid & 63, wid = tid >> 6;
  const int wr = wid >> 2, wc = wid & 3;       // 2 x 4 wave grid
  const int l15 = l & 15, l4 = l >> 4;
  const int swz = (l & 7) << 4;                // lane-constant row-XOR
  const int colp[2] = { (l4 * 16) ^ swz, (64 + l4 * 16) ^ swz };
  const int m0 = blockIdx.x * 256, n0 = blockIdx.y * 256;
  const int aoff = wr * 16384 + l15 * 128;                          // A: half=wr
  const int boff = 65536 + (wc >> 1) * 16384 + ((wc & 1) * 64 + l15) * 128;
  const int colsel = ((tid & 7) ^ ((tid >> 3) & 7)) * 16;
  const char* gA_ = (const char*)Z + ((size_t)(m0 + (tid >> 3)) << 12) + colsel;
  const char* gB_ = (const char*)Wt + ((size_t)(n0 + (tid >> 3)) << 12) + colsel;

  fx4 acc[8][4] = {};
  ix4 af[4][2], bf[4][2];

#define STAGE_A(tt, h)                                                       \
  do {                                                                       \
    const char* g = gA_ + ((size_t)((h) * 128) << 12) + (size_t)(tt) * 128;  \
    char* d = lds + (((tt) & 1) * 32768) + (h) * 16384 + tid * 16;           \
    gll16(g, d);                                                             \
    gll16(g + ((size_t)64 << 12), d + 8192);                                 \
  } while (0)
#define STAGE_B(tt, h)                                                       \
  do {                                                                       \
    const char* g = gB_ + ((size_t)((h) * 128) << 12) + (size_t)(tt) * 128;  \
    char* d = lds + 65536 + (((tt) & 1) * 32768) + (h) * 16384 + tid * 16;   \
    gll16(g, d);                                                             \
    gll16(g + ((size_t)64 << 12), d + 8192);                                 \
  } while (0)
#define LDA(mh)                                                              \
  _Pragma("unroll") for (int mf = 0; mf < 4; ++mf)                           \
    _Pragma("unroll") for (int ks = 0; ks < 2; ++ks)                         \
      af[mf][ks] = *(const ix4*)(lb + aoff + ((mh)*4 + mf) * 2048 + colp[ks]);
#define LDB(nh)                                                              \
  _Pragma("unroll") for (int nf = 0; nf < 2; ++nf)                           \
    _Pragma("unroll") for (int ks = 0; ks < 2; ++ks)                         \
      bf[(nh)*2 + nf][ks] = *(const ix4*)(lb + boff + ((nh)*2 + nf) * 2048 + colp[ks]);
#define MFMA_QUAD(mh, nh)                                                    \
  do {                                                                       \
    __builtin_amdgcn_s_setprio(1);                                           \
    _Pragma("unroll") for (int ks = 0; ks < 2; ++ks)                         \
      _Pragma("unroll") for (int mf = 0; mf < 4; ++mf)                       \
        _Pragma("unroll") for (int nf = 0; nf < 2; ++nf)                     \
          mfma16(acc[(mh)*4 + mf][(nh)*2 + nf], af[mf][ks], bf[(nh)*2 + nf][ks]); \
    __builtin_amdgcn_s_setprio(0);                                           \
  } while (0)
#define SBAR asm volatile("s_barrier" ::: "memory")

  STAGE_A(0, 0); STAGE_A(0, 1); STAGE_B(0, 0); STAGE_B(0, 1);
  STAGE_B(1, 0); STAGE_B(1, 1);
  asm volatile("s_waitcnt vmcnt(4)" ::: "memory");
  SBAR;

  for (int t = 0; t < 32; ++t) {
    const char* lb = lds + (t & 1) * 32768;
    LDA(0); LDB(0);
    if (t < 31) STAGE_A(t + 1, 0);
    SBAR;
    asm volatile("s_waitcnt lgkmcnt(0)" ::: "memory");
    MFMA_QUAD(0, 0);
    SBAR;
    LDB(1);
    if (t < 31) STAGE_A(t + 1, 1);
    SBAR;
    asm volatile("s_waitcnt lgkmcnt(0)" ::: "memory");
    MFMA_QUAD(0, 1);
    SBAR;
    LDA(1);
    if (t < 30) STAGE_B(t + 2, 0);
    SBAR;
    asm volatile("s_waitcnt lgkmcnt(0)" ::: "memory");
    MFMA_QUAD(1, 0);
    SBAR;
    if (t < 30) STAGE_B(t + 2, 1);
    SBAR;
    MFMA_QUAD(1, 1);
    if (t < 30) asm volatile("s_waitcnt vmcnt(4)" ::: "memory");
    else        asm volatile("s_waitcnt vmcnt(0)" ::: "memory");
    SBAR;
  }

#undef STAGE_A
#undef STAGE_B
#undef LDA
#undef LDB
#undef MFMA_QUAD
#undef SBAR

  const int crow = l4 * 4;
#pragma unroll
  for (int MF = 0; MF < 8; ++MF)
#pragma unroll
    for (int NF = 0; NF < 4; ++NF)
#pragma unroll
      for (int j = 0; j < 4; ++j) {
        const int r = m0 + wr * 128 + MF * 16 + crow + j;
        const int c = n0 + wc * 64 + NF * 16 + l15;
        Y[(size_t)r * NN + c] = acc[MF][NF][j];
      }
}

// ---------------------------------------------------------------- kernel 5
__global__ __launch_bounds__(256) void gather_k(float* __restrict__ Y,
                                                const int* __restrict__ ridx) {
  __shared__ __align__(16) float rowbuf[NN];
  const int tb = blockIdx.x;      // 0..8191
  const int t = tb >> 5;
  float* yrow = Y + (size_t)tb * NN;
  const int tid = threadIdx.x;
#pragma unroll
  for (int i = 0; i < 2; ++i) {
    int u = tid + i * 256;
    ((fx4*)rowbuf)[u] = ((const fx4*)yrow)[u];
  }
  __syncthreads();
  const int* ir = ridx + t * NN;
#pragma unroll
  for (int i = 0; i < 8; ++i) {
    int j = tid + i * 256;
    yrow[j] = rowbuf[ir[j]];
  }
}

// ---------------------------------------------------------------- launcher
extern "C" void kernel_launch(void* const* d_in, const int* in_sizes, int n_in,
                              void* d_out, int out_size, void* d_ws, size_t ws_size,
                              hipStream_t stream) {
  const float* x      = (const float*)d_in[0];
  const float* W_in   = (const float*)d_in[1];
  const float* bias   = (const float*)d_in[2];
  const float* W_bern = (const float*)d_in[3];
  const int*   ridx   = (const int*)d_in[4];
  float* out = (float*)d_out;
  char* ws = (char*)d_ws;

  __hip_bfloat16* Wt = (__hip_bfloat16*)ws;                       // 8,388,608 B
  __hip_bfloat16* Zb = (__hip_bfloat16*)(ws + (size_t)8388608);   // 33,554,432 B
  const size_t offI = 41943040;                                   // I: 67,108,864 B
  const bool sep = ws_size >= (size_t)109051904;
  float* Ibuf = sep ? (float*)(ws + offI) : (out + (size_t)TBN);

  wt_convert<<<dim3(64, 64), dim3(32, 8), 0, stream>>>(W_bern, Wt);
  in_gemm<<<dim3(256, 8), dim3(256), 0, stream>>>(x, W_in, bias, Ibuf);
  if (sep)
    scan_sep<<<dim3(256), dim3(256), 0, stream>>>(out, Ibuf, Zb);
  else
    scan_inp<<<dim3(256), dim3(256), 0, stream>>>(out, Zb);
  bern_gemm<<<dim3(32, 8), dim3(512), 0, stream>>>(Zb, Wt, out + (size_t)2 * TBN);
  gather_k<<<dim3(8192), dim3(256), 0, stream>>>(out + (size_t)2 * TBN, ridx);
}